// Round 1
// baseline (130.976 us; speedup 1.0000x reference)
//
#include <hip/hip_runtime.h>
#include <cmath>

#define N_ROWS 2048
#define DIM 4096
#define ROW_STRIDE 8192   // features[:,0,:] -> row i at offset i*2*4096
#define NCLS 8

__device__ __forceinline__ float wred_sum(float v){
  #pragma unroll
  for(int o=32;o>0;o>>=1) v += __shfl_xor(v,o,64);
  return v;
}
__device__ __forceinline__ float wred_max(float v){
  #pragma unroll
  for(int o=32;o>0;o>>=1) v = fmaxf(v,__shfl_xor(v,o,64));
  return v;
}

// One block per row: compute lse[row], diag[row] = sum p*logp.
// Blocks 0..63 also zero the 65536-float P/L accumulator region.
__global__ __launch_bounds__(256) void k1_rowstats(
    const float* __restrict__ feat, float* __restrict__ lse,
    float* __restrict__ diag, float* __restrict__ zero_region){
  const int t = threadIdx.x;
  const int row = blockIdx.x;
  if(row < 64){
    float4* z = (float4*)zero_region;
    z[row*256 + t] = make_float4(0.f,0.f,0.f,0.f);
  }
  const float4* x4 = (const float4*)(feat + (size_t)row * ROW_STRIDE);
  float4 v[4];
  #pragma unroll
  for(int k=0;k<4;k++) v[k] = x4[t + k*256];

  __shared__ float red[4];
  // ---- max ----
  float m = -INFINITY;
  #pragma unroll
  for(int k=0;k<4;k++)
    m = fmaxf(m, fmaxf(fmaxf(v[k].x,v[k].y), fmaxf(v[k].z,v[k].w)));
  m = wred_max(m);
  if((t & 63)==0) red[t>>6] = m;
  __syncthreads();
  m = fmaxf(fmaxf(red[0],red[1]), fmaxf(red[2],red[3]));
  __syncthreads();
  // ---- sum exp ----
  float s = 0.f;
  #pragma unroll
  for(int k=0;k<4;k++)
    s += __expf(v[k].x - m) + __expf(v[k].y - m)
       + __expf(v[k].z - m) + __expf(v[k].w - m);
  s = wred_sum(s);
  if((t&63)==0) red[t>>6] = s;
  __syncthreads();
  s = red[0]+red[1]+red[2]+red[3];
  __syncthreads();
  const float l = m + __logf(s);
  // ---- diag = sum (x-l)*exp(x-l) ----
  float dg = 0.f;
  #pragma unroll
  for(int k=0;k<4;k++){
    float a=v[k].x-l, b=v[k].y-l, c=v[k].z-l, d2=v[k].w-l;
    dg += a*__expf(a) + b*__expf(b) + c*__expf(c) + d2*__expf(d2);
  }
  dg = wred_sum(dg);
  if((t&63)==0) red[t>>6] = dg;
  __syncthreads();
  if(t==0){
    lse[row] = l;
    diag[row] = red[0]+red[1]+red[2]+red[3];
  }
}

// grid (DIM/256, 32): thread owns column d, iterates a 64-row chunk,
// accumulates per-class P (sum of p) and L (sum of logp) in registers,
// then 16 global atomics.
__global__ __launch_bounds__(256) void k2_accum(
    const float* __restrict__ feat, const float* __restrict__ lse,
    const int* __restrict__ labels,
    float* __restrict__ Pbuf, float* __restrict__ Lbuf){
  const int d = blockIdx.x * 256 + threadIdx.x;
  const int r0 = blockIdx.y * 64;
  float P0=0,P1=0,P2=0,P3=0,P4=0,P5=0,P6=0,P7=0;
  float L0=0,L1=0,L2=0,L3=0,L4=0,L5=0,L6=0,L7=0;
  const float* col = feat + (size_t)r0 * ROW_STRIDE + d;
  #pragma unroll 4
  for(int i=0;i<64;i++){
    const int r = r0 + i;
    float x = col[(size_t)i * ROW_STRIDE];
    float v = x - lse[r];
    float e = __expf(v);
    int lab = __builtin_amdgcn_readfirstlane(labels[r]); // wave-uniform -> scalar branch
    switch(lab){
      case 0: P0+=e; L0+=v; break;
      case 1: P1+=e; L1+=v; break;
      case 2: P2+=e; L2+=v; break;
      case 3: P3+=e; L3+=v; break;
      case 4: P4+=e; L4+=v; break;
      case 5: P5+=e; L5+=v; break;
      case 6: P6+=e; L6+=v; break;
      default: P7+=e; L7+=v; break;
    }
  }
  atomicAdd(&Pbuf[0*DIM+d],P0); atomicAdd(&Lbuf[0*DIM+d],L0);
  atomicAdd(&Pbuf[1*DIM+d],P1); atomicAdd(&Lbuf[1*DIM+d],L1);
  atomicAdd(&Pbuf[2*DIM+d],P2); atomicAdd(&Lbuf[2*DIM+d],L2);
  atomicAdd(&Pbuf[3*DIM+d],P3); atomicAdd(&Lbuf[3*DIM+d],L3);
  atomicAdd(&Pbuf[4*DIM+d],P4); atomicAdd(&Lbuf[4*DIM+d],L4);
  atomicAdd(&Pbuf[5*DIM+d],P5); atomicAdd(&Lbuf[5*DIM+d],L5);
  atomicAdd(&Pbuf[6*DIM+d],P6); atomicAdd(&Lbuf[6*DIM+d],L6);
  atomicAdd(&Pbuf[7*DIM+d],P7); atomicAdd(&Lbuf[7*DIM+d],L7);
}

// Single block: per-class D_c, n_c; S_same = sum_c sum_d P_c*L_c;
// S_all = sum_d (sum_c P)(sum_c L); combine in fp64.
__global__ __launch_bounds__(256) void k3_final(
    const float* __restrict__ diag, const int* __restrict__ labels,
    const float* __restrict__ Pbuf, const float* __restrict__ Lbuf,
    float* __restrict__ out){
  const int t = threadIdx.x;
  const int wave = t>>6, lane = t&63;
  double Dl[8]; int Nl[8];
  #pragma unroll
  for(int c=0;c<8;c++){ Dl[c]=0.0; Nl[c]=0; }
  for(int i=t;i<N_ROWS;i+=256){
    int lab = labels[i];
    double dg = (double)diag[i];
    #pragma unroll
    for(int c=0;c<8;c++){
      if(lab==c){ Dl[c]+=dg; Nl[c]++; }
    }
  }
  #pragma unroll
  for(int c=0;c<8;c++){
    #pragma unroll
    for(int o=32;o>0;o>>=1){
      Dl[c] += __shfl_xor(Dl[c],o,64);
      Nl[c] += __shfl_xor(Nl[c],o,64);
    }
  }
  __shared__ double sD[4][8];
  __shared__ int    sN[4][8];
  if(lane==0){
    #pragma unroll
    for(int c=0;c<8;c++){ sD[wave][c]=Dl[c]; sN[wave][c]=Nl[c]; }
  }
  __syncthreads();
  __shared__ double D[8]; __shared__ int Ncnt[8];
  if(t<8){
    D[t]    = sD[0][t]+sD[1][t]+sD[2][t]+sD[3][t];
    Ncnt[t] = sN[0][t]+sN[1][t]+sN[2][t]+sN[3][t];
  }
  __syncthreads();

  double acc_same=0.0, acc_all=0.0;
  for(int dd=t; dd<DIM; dd+=256){
    double ps=0.0, ls=0.0;
    #pragma unroll
    for(int c=0;c<8;c++){
      float p  = Pbuf[c*DIM+dd];
      float lq = Lbuf[c*DIM+dd];
      acc_same += (double)p*(double)lq;
      ps += (double)p; ls += (double)lq;
    }
    acc_all += ps*ls;
  }
  #pragma unroll
  for(int o=32;o>0;o>>=1){
    acc_same += __shfl_xor(acc_same,o,64);
    acc_all  += __shfl_xor(acc_all,o,64);
  }
  __shared__ double sS[4], sA[4];
  if(lane==0){ sS[wave]=acc_same; sA[wave]=acc_all; }
  __syncthreads();
  if(t==0){
    double S_same = sS[0]+sS[1]+sS[2]+sS[3];
    double S_all  = sA[0]+sA[1]+sA[2]+sA[3];
    double same_num=0.0, diff_num=0.0;
    for(int c=0;c<8;c++){
      same_num += (double)Ncnt[c]*D[c];
      diff_num += (double)(N_ROWS - Ncnt[c])*D[c];
    }
    same_num -= S_same;            // = same_sum * 2d
    diff_num -= (S_all - S_same);  // = diff_sum * 2d
    out[0] = (float)(same_num/diff_num);
  }
}

extern "C" void kernel_launch(void* const* d_in, const int* in_sizes, int n_in,
                              void* d_out, int out_size, void* d_ws, size_t ws_size,
                              hipStream_t stream){
  const float* feat   = (const float*)d_in[0];
  const int*   labels = (const int*)d_in[1];
  float* out = (float*)d_out;
  float* ws  = (float*)d_ws;
  float* lse  = ws;                    // 2048
  float* diag = ws + N_ROWS;           // 2048
  float* Pbuf = ws + 2*N_ROWS;         // 8*4096  (16 KiB offset -> float4 aligned)
  float* Lbuf = Pbuf + NCLS*DIM;       // 8*4096  (contiguous after Pbuf)

  k1_rowstats<<<N_ROWS, 256, 0, stream>>>(feat, lse, diag, Pbuf);
  k2_accum<<<dim3(DIM/256, 32), 256, 0, stream>>>(feat, lse, labels, Pbuf, Lbuf);
  k3_final<<<1, 256, 0, stream>>>(diag, labels, Pbuf, Lbuf, out);
}